// Round 12
// baseline (86.911 us; speedup 1.0000x reference)
//
#include <hip/hip_runtime.h>

#define NPTS 8192
#define NB 4

// ---------------- fused-kernel configuration ----------------
#define WPB 8                               // waves per block (512 threads)
#define ITILES 4                            // 16-row MFMA tiles per wave
#define ROWS_PER_WAVE (ITILES * 16)         // 64
#define ROWS_PER_BLOCK (WPB * ROWS_PER_WAVE)// 512
#define CHUNK 512                           // cols per block
#define JT (CHUNK / 16)                     // 32 col tiles
#define CHUNKS (NPTS / CHUNK)               // 16
#define ROWBLKS (NPTS / ROWS_PER_BLOCK)     // 16

using bf16x4 = __attribute__((ext_vector_type(4))) short;
using bf16x8 = __attribute__((ext_vector_type(8))) short;
using f32x4  = __attribute__((ext_vector_type(4))) float;

// K=16 MFMA if available; otherwise zero-padded K=32 fallback — same record
// layout, still correct. (Round-11 verified: absmax 0.0 either way.)
#if __has_builtin(__builtin_amdgcn_mfma_f32_16x16x16bf16_1k)
#define HAVE_MFMA16 1
typedef bf16x4 afrag;
#define MFMA_BF16(a, b, c) __builtin_amdgcn_mfma_f32_16x16x16bf16_1k(a, b, c, 0, 0, 0)
#else
#define HAVE_MFMA16 0
typedef bf16x8 afrag;
#define MFMA_BF16(a, b, c) __builtin_amdgcn_mfma_f32_16x16x32_bf16(a, b, c, 0, 0, 0)
#endif

// bf16 round-to-nearest-even, manual
__device__ __forceinline__ unsigned short bfb(float v) {
    unsigned int x = __float_as_uint(v);
    return (unsigned short)((x + 0x7FFFu + ((x >> 16) & 1u)) >> 16);
}
__device__ __forceinline__ float bff(unsigned short u) {
    return __uint_as_float(((unsigned int)u) << 16);
}
// 2-way bf16 split: v ~= H + M, |v - H - M| <= 2^-18 |v|
__device__ __forceinline__ void split2(float v, unsigned short& H, unsigned short& M) {
    H = bfb(v); M = bfb(v - bff(H));
}
__device__ __forceinline__ unsigned int pk(unsigned short lo, unsigned short hi) {
    return (unsigned int)lo | ((unsigned int)hi << 16);
}
__device__ __forceinline__ unsigned int umn(unsigned int a, unsigned int b) {
    return a < b ? a : b;
}

// K=16 record = 32 B/point. Per coord (4 slots): A=[aH aH aM aM], B=[tH tM tH tM]
// -> (aH+aM)(tH+tM). Slots 12..13: A=[ppH ppM], B=[1 1]; 14..15: A=[1 1],
// B=[ttH ttM]. dot(A,B) = |p|^2 - 2p.t + |t|^2 to ~2^-18 rel per term.
__device__ __forceinline__ void encA16(float x, float y, float z, char* base) {
    const unsigned short ONE = 0x3F80u;
    float pp = fmaf(x, x, fmaf(y, y, z * z));
    unsigned short xH,xM, yH,yM, zH,zM, pH,pM;
    split2(-2.f * x, xH, xM);
    split2(-2.f * y, yH, yM);
    split2(-2.f * z, zH, zM);
    split2(pp, pH, pM);
    uint4 q0 = make_uint4(pk(xH,xH), pk(xM,xM), pk(yH,yH), pk(yM,yM));
    uint4 q1 = make_uint4(pk(zH,zH), pk(zM,zM), pk(pH,pM), pk(ONE,ONE));
    *(uint4*)(base +  0) = q0;
    *(uint4*)(base + 16) = q1;
}
__device__ __forceinline__ void encB16(float x, float y, float z, char* base) {
    const unsigned short ONE = 0x3F80u;
    float pp = fmaf(x, x, fmaf(y, y, z * z));
    unsigned short xH,xM, yH,yM, zH,zM, pH,pM;
    split2(x, xH, xM);
    split2(y, yH, yM);
    split2(z, zH, zM);
    split2(pp, pH, pM);
    unsigned int wx = pk(xH,xM), wy = pk(yH,yM), wz = pk(zH,zM);
    uint4 q0 = make_uint4(wx, wx, wy, wy);
    uint4 q1 = make_uint4(wz, wz, pk(ONE,ONE), pk(pH,pM));
    *(uint4*)(base +  0) = q0;
    *(uint4*)(base + 16) = q1;
}

// Load this lane's fragment from a 32 B record: rec = tile_base + (idx&15)*32.
__device__ __forceinline__ afrag ld_frag(const char* rec, int hi) {
#if HAVE_MFMA16
    return *(const afrag*)(rec + hi * 8);      // k-seg = hi*4 .. hi*4+3
#else
    if (hi < 2) return *(const afrag*)(rec + hi * 16);  // slots 0..15 live
    afrag z = {0,0,0,0,0,0,0,0};               // K 16..31 zero-padded
    return z;
#endif
}

// ---------------------------------------------------------------------------
// 4-wide tile group: 16 INDEPENDENT MFMAs (4 af x 4 B), then 2-level fold
// trees (4-input min per element) — triple the independent work between
// dependent ops vs the old 2-wide chain. Col partials: full-wave LDS
// atomicMin into colh[col][hi] (64 distinct addrs/wave, 2/bank = free).
// ---------------------------------------------------------------------------
__device__ __forceinline__ void tile_quad(
    const afrag (&af)[ITILES], const afrag (&Bf)[4],
    f32x4 (&rmin)[ITILES], unsigned int* colh, int cbase)
{
    const f32x4 zf = {0.f, 0.f, 0.f, 0.f};
    f32x4 d[4][4];
#pragma unroll
    for (int it = 0; it < 4; ++it)
#pragma unroll
        for (int bj = 0; bj < 4; ++bj)
            d[it][bj] = MFMA_BF16(af[it], Bf[bj], zf);

    // row folds: 4-input tree per element
#pragma unroll
    for (int it = 0; it < 4; ++it)
#pragma unroll
        for (int r = 0; r < 4; ++r) {
            float m01 = fminf(d[it][0][r], d[it][1][r]);
            float m23 = fminf(d[it][2][r], d[it][3][r]);
            rmin[it][r] = fminf(rmin[it][r], fminf(m01, m23));
        }

    // col folds: 4-input tree over row-tiles, collapse, one atomic per bj
#pragma unroll
    for (int bj = 0; bj < 4; ++bj) {
        float cp0 = fminf(fminf(d[0][bj][0], d[1][bj][0]),
                          fminf(d[2][bj][0], d[3][bj][0]));
        float cp1 = fminf(fminf(d[0][bj][1], d[1][bj][1]),
                          fminf(d[2][bj][1], d[3][bj][1]));
        float cp2 = fminf(fminf(d[0][bj][2], d[1][bj][2]),
                          fminf(d[2][bj][2], d[3][bj][2]));
        float cp3 = fminf(fminf(d[0][bj][3], d[1][bj][3]),
                          fminf(d[2][bj][3], d[3][bj][3]));
        float c = fminf(fminf(cp0, cp1), fminf(cp2, cp3));
        c = fmaxf(c, 0.f);               // bit-pattern uint-min == float-min
        atomicMin(&colh[cbase + bj * 64], __float_as_uint(c));
    }
}

// ---------------------------------------------------------------------------
// Fused kernel, round-12: 4-wide main loop (8 outer iterations), 4-deep B
// prefetch. launch_bounds(512,4) raises VGPR cap to 128 for the d[4][4]
// tile block (~110 VGPR live); LDS unchanged (40960 B, 4 blocks/CU).
// All other phases identical to round 11 (passed, absmax 0.0).
// ---------------------------------------------------------------------------
__global__ __launch_bounds__(512, 4) void chamfer_fused(
    const float* __restrict__ pred, const float* __restrict__ target,
    float* __restrict__ rowpart, float* __restrict__ colpart,
    float* __restrict__ out, const float* __restrict__ bpp,
    const float* __restrict__ lamda)
{
    __shared__ short bB[16384];                  // 32768 B multi-purpose
    __shared__ unsigned int colh[CHUNK * 4];     // 8192 B: [col][hi]

    const int tid  = threadIdx.x;
    const int lane = tid & 63;
    const int w    = tid >> 6;                   // 0..7
    const int bid  = blockIdx.x;
    const int ck   = bid & (CHUNKS - 1);
    const int rb   = (bid >> 4) & (ROWBLKS - 1);
    const int b    = bid >> 8;

    const int col0 = ck * CHUNK;
    const float* asrc = pred   + (size_t)b * NPTS * 3;
    const float* bsrc = target + (size_t)b * NPTS * 3;

    // ---- hoisted global loads: 1 A-row + 1 B-col per thread
    const int ag = rb * ROWS_PER_BLOCK + tid;
    float ax = asrc[3 * ag + 0], ay = asrc[3 * ag + 1], az = asrc[3 * ag + 2];
    const int bg = col0 + tid;
    float bx = bsrc[3 * bg + 0], by = bsrc[3 * bg + 1], bz = bsrc[3 * bg + 2];

    if (bid == 0 && tid == 0) out[0] = lamda[0] * bpp[0];  // init for atomicAdd

    for (int i = tid; i < CHUNK * 4; i += 512) colh[i] = 0x7F7F7F7Fu;

    // ---- Phase 1: A-encode, wave-local 2 KB region: record for row
    //      (w*64 + lane) at w*2048 + (lane>>4)*512 + (lane&15)*32.
    encA16(ax, ay, az,
           (char*)bB + w * 2048 + (lane >> 4) * 512 + (lane & 15) * 32);

    // ---- Phase 2: wave-local A readback (same wave wrote it; lgkmcnt only)
    afrag af[ITILES];
    {
        const char* ab = (const char*)bB + w * 2048 + (lane & 15) * 32;
        const int hi = lane >> 4;
#pragma unroll
        for (int it = 0; it < ITILES; ++it)
            af[it] = ld_frag(ab + it * 512, hi);
    }
    __syncthreads();   // all waves done reading A before B overwrites bB

    // ---- Phase 3: B-encode from hoisted registers (1 col per thread):
    //      tile tid>>4, col-in-tile tid&15 -> 32 tiles x 512 B = 16 KB.
    encB16(bx, by, bz, (char*)bB + (tid >> 4) * 512 + (tid & 15) * 32);

    f32x4 rmin[ITILES];
#pragma unroll
    for (int it = 0; it < ITILES; ++it) {
        rmin[it][0] = 3e38f; rmin[it][1] = 3e38f;
        rmin[it][2] = 3e38f; rmin[it][3] = 3e38f;
    }

    __syncthreads();  // B encode + colh init visible

    // ---- Phase 4: main loop, 4 tiles/iter, 4-deep prefetch, wrap-clamped
    const char* bb = (const char*)bB + (lane & 15) * 32;
    const int hi = lane >> 4;
    afrag Bc[4], Bn[4];
#pragma unroll
    for (int t = 0; t < 4; ++t) Bc[t] = ld_frag(bb + t * 512, hi);
    int cbase = (lane & 15) * 4 + hi;               // colh idx = col*4 + hi
    for (int jt = 0; jt < JT; jt += 4) {
        int nj = (jt + 4) & (JT - 1);               // last iter wraps: valid
#pragma unroll
        for (int t = 0; t < 4; ++t)                 // addr, value unused
            Bn[t] = ld_frag(bb + (nj + t) * 512, hi);
        tile_quad(af, Bc, rmin, colh, cbase);
        cbase += 256;                               // 64 cols * 4
#pragma unroll
        for (int t = 0; t < 4; ++t) Bc[t] = Bn[t];
    }

    __syncthreads();   // main loop done: bB (B-tiles) dead, colh complete

    // ---- row-min epilogue (round-9 verified): stage rmin through bB,
    //      wave-local, 2 passes, stride-80 rows, b128 readback, 1 shfl.
    {
        char* sb = (char*)bB + w * 2560;          // 8 waves x 2560 = 20 KB
        const int hig = lane >> 4, col = lane & 15;
#pragma unroll
        for (int p = 0; p < 2; ++p) {
#pragma unroll
            for (int halfit = 0; halfit < 2; ++halfit) {
#pragma unroll
                for (int r = 0; r < 4; ++r) {
                    int row32 = halfit * 16 + hig * 4 + r;
                    *(float*)(sb + row32 * 80 + col * 4) = rmin[p * 2 + halfit][r];
                }
            }
            const int a = lane >> 1, bsel = lane & 1;
            const char* rp = sb + a * 80 + bsel * 32;
            f32x4 v0 = *(const f32x4*)(rp);
            f32x4 v1 = *(const f32x4*)(rp + 16);
            float v = fminf(fminf(fminf(v0[0], v0[1]), fminf(v0[2], v0[3])),
                            fminf(fminf(v1[0], v1[1]), fminf(v1[2], v1[3])));
            v = fminf(v, __shfl_xor(v, 1, 64));
            if (bsel == 0) {
                int row = rb * ROWS_PER_BLOCK + w * ROWS_PER_WAVE + p * 32 + a;
                rowpart[((size_t)(b * CHUNKS) + ck) * NPTS + row] = fmaxf(v, 0.f);
            }
            __builtin_amdgcn_sched_barrier(0);   // pin pass-1 writes after pass-0 reads
        }
    }

    // ---- col epilogue: merge 4 hi-groups (one uint4 read), coalesced store
    for (int i = tid; i < CHUNK; i += 512) {
        uint4 v = *(const uint4*)&colh[i * 4];
        unsigned int m = umn(umn(v.x, v.y), umn(v.z, v.w));
        colpart[((size_t)(b * ROWBLKS) + rb) * NPTS + col0 + i] = __uint_as_float(m);
    }
}

// min over 16 slices per row/col cell, block-sum, one atomicAdd per block.
// out was initialized to lamda*bpp by chamfer_fused (stream-ordered).
__global__ __launch_bounds__(256) void reduce_partials(
    const float* __restrict__ rowpart, const float* __restrict__ colpart,
    float* __restrict__ out)
{
    const int tid = threadIdx.x;
    const int gt  = blockIdx.x * 256 + tid;    // 0..16383
    float s = 0.f;
#pragma unroll
    for (int a = 0; a < 2; a++) {
        const float* P = a ? colpart : rowpart;
#pragma unroll
        for (int cc = 0; cc < 2; cc++) {
            int c = gt + cc * 16384;           // 0..32767
            int b = c >> 13, r = c & 8191;
            const float* p = P + (size_t)b * 16 * NPTS + r;
            float m = p[0];
#pragma unroll
            for (int k = 1; k < 16; k++)
                m = fminf(m, p[(size_t)k * NPTS]);
            s += m;
        }
    }
#pragma unroll
    for (int off = 32; off > 0; off >>= 1) s += __shfl_down(s, off, 64);
    __shared__ float red[4];
    int lane = tid & 63, wid = tid >> 6;
    if (lane == 0) red[wid] = s;
    __syncthreads();
    if (tid == 0)
        atomicAdd(out, (red[0] + red[1] + red[2] + red[3]) * (1.0f / 32768.0f));
}

// ---------------------------------------------------------------------------
// Fallback: VALU kernel + atomic partmin (tiny workspace only)
// ---------------------------------------------------------------------------
#define T 256
#define Q 8
#define S 16
#define CH 512
#define NCOMBO 8

__global__ __launch_bounds__(T) void chamfer_partial(
    const float* __restrict__ pred, const float* __restrict__ target,
    unsigned int* __restrict__ partmin)
{
    __shared__ float4 db[CH + 2];

    const int bid   = blockIdx.x;
    const int dbc   = bid & (S - 1);
    const int qc    = (bid >> 4) & 3;
    const int combo = bid >> 6;
    const int dir   = combo & 1;
    const int b     = combo >> 1;

    const float* qptr = (dir == 0 ? pred : target) + (size_t)b * NPTS * 3;
    const float* dptr = (dir == 0 ? target : pred) + (size_t)b * NPTS * 3;

    const int tid = threadIdx.x;

    for (int p = tid; p < CH; p += T) {
        int gj = dbc * CH + p;
        float x = dptr[gj * 3 + 0];
        float y = dptr[gj * 3 + 1];
        float z = dptr[gj * 3 + 2];
        db[p] = make_float4(-2.f * x, -2.f * y, -2.f * z,
                            x * x + y * y + z * z);
    }

    float qx[Q], qy[Q], qz[Q], m[Q];
    int qi0 = qc * (T * Q) + tid;
#pragma unroll
    for (int k = 0; k < Q; k++) {
        int qi = qi0 + k * T;
        qx[k] = qptr[qi * 3 + 0];
        qy[k] = qptr[qi * 3 + 1];
        qz[k] = qptr[qi * 3 + 2];
        m[k]  = 3.4e38f;
    }
    __syncthreads();

    float4 c0 = db[0], c1 = db[1];
    for (int j = 0; j < CH; j += 2) {
        float4 n0 = db[j + 2];
        float4 n1 = db[j + 3];
#pragma unroll
        for (int k = 0; k < Q; k++) {
            float s0 = fmaf(c0.x, qx[k], fmaf(c0.y, qy[k], fmaf(c0.z, qz[k], c0.w)));
            float s1 = fmaf(c1.x, qx[k], fmaf(c1.y, qy[k], fmaf(c1.z, qz[k], c1.w)));
            m[k] = fminf(m[k], fminf(s0, s1));
        }
        c0 = n0; c1 = n1;
    }

#pragma unroll
    for (int k = 0; k < Q; k++) {
        int qi = qi0 + k * T;
        float qq = fmaf(qx[k], qx[k], fmaf(qy[k], qy[k], qz[k] * qz[k]));
        float d2 = fmaxf(m[k] + qq, 0.0f);
        atomicMin(&partmin[combo * NPTS + qi], __float_as_uint(d2));
    }
}

__global__ __launch_bounds__(1024) void reduce_final(
    const unsigned int* __restrict__ partmin,
    const float* __restrict__ bpp, const float* __restrict__ lamda,
    float* __restrict__ out)
{
    const int tid = threadIdx.x;
    float s = 0.f;
#pragma unroll
    for (int k = 0; k < (NCOMBO * NPTS) / 1024; k++)
        s += __uint_as_float(partmin[tid + k * 1024]);

#pragma unroll
    for (int off = 32; off > 0; off >>= 1)
        s += __shfl_down(s, off, 64);

    __shared__ float red[16];
    int lane = tid & 63, wid = tid >> 6;
    if (lane == 0) red[wid] = s;
    __syncthreads();
    if (wid == 0) {
        s = (lane < 16) ? red[lane] : 0.f;
#pragma unroll
        for (int off = 8; off > 0; off >>= 1)
            s += __shfl_down(s, off, 64);
        if (lane == 0)
            out[0] = s * (1.0f / 32768.0f) + lamda[0] * bpp[0];
    }
}

extern "C" void kernel_launch(void* const* d_in, const int* in_sizes, int n_in,
                              void* d_out, int out_size, void* d_ws, size_t ws_size,
                              hipStream_t stream) {
    const float* pred   = (const float*)d_in[0];
    const float* target = (const float*)d_in[1];
    const float* bpp    = (const float*)d_in[2];
    const float* lamda  = (const float*)d_in[3];

    const size_t part_bytes = (size_t)NB * 16 * NPTS * sizeof(float);  // 2 MB

    if (ws_size >= 2 * part_bytes) {
        float* rowpart = (float*)d_ws;
        float* colpart = rowpart + (size_t)NB * 16 * NPTS;
        chamfer_fused<<<NB * ROWBLKS * CHUNKS, 512, 0, stream>>>(
            pred, target, rowpart, colpart, (float*)d_out, bpp, lamda);
        reduce_partials<<<64, 256, 0, stream>>>(rowpart, colpart, (float*)d_out);
    } else {
        unsigned int* partmin = (unsigned int*)d_ws;
        hipMemsetAsync(partmin, 0x7F, (size_t)NCOMBO * NPTS * sizeof(unsigned int),
                       stream);
        chamfer_partial<<<NCOMBO * 4 * S, T, 0, stream>>>(pred, target, partmin);
        reduce_final<<<1, 1024, 0, stream>>>(partmin, bpp, lamda, (float*)d_out);
    }
}

// Round 13
// 79.394 us; speedup vs baseline: 1.0947x; 1.0947x over previous
//
#include <hip/hip_runtime.h>

#define NPTS 8192
#define NB 4

// ---------------- fused-kernel configuration ----------------
#define WPB 8                               // waves per block (512 threads)
#define ITILES 4                            // 16-row MFMA tiles per wave
#define ROWS_PER_WAVE (ITILES * 16)         // 64
#define ROWS_PER_BLOCK (WPB * ROWS_PER_WAVE)// 512
#define CHUNK 512                           // cols per block
#define JT (CHUNK / 16)                     // 32 col tiles
#define CHUNKS (NPTS / CHUNK)               // 16
#define ROWBLKS (NPTS / ROWS_PER_BLOCK)     // 16

using bf16x4 = __attribute__((ext_vector_type(4))) short;
using bf16x8 = __attribute__((ext_vector_type(8))) short;
using f32x4  = __attribute__((ext_vector_type(4))) float;

// K=16 MFMA if available (round-11 verified: absmax 0.0, best total 80.7us);
// otherwise zero-padded K=32 fallback — same record layout, still correct.
#if __has_builtin(__builtin_amdgcn_mfma_f32_16x16x16bf16_1k)
#define HAVE_MFMA16 1
typedef bf16x4 afrag;
#define MFMA_BF16(a, b, c) __builtin_amdgcn_mfma_f32_16x16x16bf16_1k(a, b, c, 0, 0, 0)
#else
#define HAVE_MFMA16 0
typedef bf16x8 afrag;
#define MFMA_BF16(a, b, c) __builtin_amdgcn_mfma_f32_16x16x32_bf16(a, b, c, 0, 0, 0)
#endif

// bf16 round-to-nearest-even, manual
__device__ __forceinline__ unsigned short bfb(float v) {
    unsigned int x = __float_as_uint(v);
    return (unsigned short)((x + 0x7FFFu + ((x >> 16) & 1u)) >> 16);
}
__device__ __forceinline__ float bff(unsigned short u) {
    return __uint_as_float(((unsigned int)u) << 16);
}
// 2-way bf16 split: v ~= H + M, |v - H - M| <= 2^-18 |v|
__device__ __forceinline__ void split2(float v, unsigned short& H, unsigned short& M) {
    H = bfb(v); M = bfb(v - bff(H));
}
__device__ __forceinline__ unsigned int pk(unsigned short lo, unsigned short hi) {
    return (unsigned int)lo | ((unsigned int)hi << 16);
}
__device__ __forceinline__ unsigned int umn(unsigned int a, unsigned int b) {
    return a < b ? a : b;
}

// K=16 record = 32 B/point. Per coord (4 slots): A=[aH aH aM aM], B=[tH tM tH tM]
// -> (aH+aM)(tH+tM). Slots 12..13: A=[ppH ppM], B=[1 1]; 14..15: A=[1 1],
// B=[ttH ttM]. dot(A,B) = |p|^2 - 2p.t + |t|^2 to ~2^-18 rel per term.
__device__ __forceinline__ void encA16(float x, float y, float z, char* base) {
    const unsigned short ONE = 0x3F80u;
    float pp = fmaf(x, x, fmaf(y, y, z * z));
    unsigned short xH,xM, yH,yM, zH,zM, pH,pM;
    split2(-2.f * x, xH, xM);
    split2(-2.f * y, yH, yM);
    split2(-2.f * z, zH, zM);
    split2(pp, pH, pM);
    uint4 q0 = make_uint4(pk(xH,xH), pk(xM,xM), pk(yH,yH), pk(yM,yM));
    uint4 q1 = make_uint4(pk(zH,zH), pk(zM,zM), pk(pH,pM), pk(ONE,ONE));
    *(uint4*)(base +  0) = q0;
    *(uint4*)(base + 16) = q1;
}
__device__ __forceinline__ void encB16(float x, float y, float z, char* base) {
    const unsigned short ONE = 0x3F80u;
    float pp = fmaf(x, x, fmaf(y, y, z * z));
    unsigned short xH,xM, yH,yM, zH,zM, pH,pM;
    split2(x, xH, xM);
    split2(y, yH, yM);
    split2(z, zH, zM);
    split2(pp, pH, pM);
    unsigned int wx = pk(xH,xM), wy = pk(yH,yM), wz = pk(zH,zM);
    uint4 q0 = make_uint4(wx, wx, wy, wy);
    uint4 q1 = make_uint4(wz, wz, pk(ONE,ONE), pk(pH,pM));
    *(uint4*)(base +  0) = q0;
    *(uint4*)(base + 16) = q1;
}

// Load this lane's fragment from a 32 B record: rec = tile_base + (idx&15)*32.
__device__ __forceinline__ afrag ld_frag(const char* rec, int hi) {
#if HAVE_MFMA16
    return *(const afrag*)(rec + hi * 8);      // k-seg = hi*4 .. hi*4+3
#else
    if (hi < 2) return *(const afrag*)(rec + hi * 16);  // slots 0..15 live
    afrag z = {0,0,0,0,0,0,0,0};               // K 16..31 zero-padded
    return z;
#endif
}

// ---------------------------------------------------------------------------
// 2x2 tile group: 8 MFMAs + fminf folds. Col partials: full-wave LDS
// atomicMin into colh[col][hi] (64 distinct addrs, 2/bank = free).
// Round-12's 4-wide variant regressed (d[4][4] reg pressure traded away
// TLP for ILP); this 2-wide form is the measured optimum.
// ---------------------------------------------------------------------------
__device__ __forceinline__ void tile_pair(
    const afrag (&af)[ITILES], afrag b0, afrag b1,
    f32x4 (&rmin)[ITILES], unsigned int* colh, int cbase,
    const f32x4& zf)
{
    f32x4 cp0 = {3e38f, 3e38f, 3e38f, 3e38f};
    f32x4 cp1 = {3e38f, 3e38f, 3e38f, 3e38f};
#pragma unroll
    for (int it = 0; it < ITILES; it += 2) {
        f32x4 d00 = MFMA_BF16(af[it],     b0, zf);
        f32x4 d01 = MFMA_BF16(af[it],     b1, zf);
        f32x4 d10 = MFMA_BF16(af[it + 1], b0, zf);
        f32x4 d11 = MFMA_BF16(af[it + 1], b1, zf);
#pragma unroll
        for (int r = 0; r < 4; ++r) {
            rmin[it][r]     = fminf(fminf(d00[r], d01[r]), rmin[it][r]);
            rmin[it + 1][r] = fminf(fminf(d10[r], d11[r]), rmin[it + 1][r]);
            cp0[r]          = fminf(fminf(d00[r], d10[r]), cp0[r]);
            cp1[r]          = fminf(fminf(d01[r], d11[r]), cp1[r]);
        }
    }
    float c0 = fminf(fminf(cp0[0], cp0[1]), fminf(cp0[2], cp0[3]));
    float c1 = fminf(fminf(cp1[0], cp1[1]), fminf(cp1[2], cp1[3]));
    c0 = fmaxf(c0, 0.f);                 // bit-pattern uint-min == float-min
    c1 = fmaxf(c1, 0.f);
    atomicMin(&colh[cbase],      __float_as_uint(c0));
    atomicMin(&colh[cbase + 64], __float_as_uint(c1));   // +16 cols * 4
}

// ---------------------------------------------------------------------------
// Fused kernel — round-11 optimum, reverted verbatim. Two dispatches total
// (round 10 proved per-block device fences cost 150+ us on 8-XCD CDNA4;
// a second dispatch is the cheap cross-XCD visibility point).
// ---------------------------------------------------------------------------
__global__ __launch_bounds__(512, 6) void chamfer_fused(
    const float* __restrict__ pred, const float* __restrict__ target,
    float* __restrict__ rowpart, float* __restrict__ colpart,
    float* __restrict__ out, const float* __restrict__ bpp,
    const float* __restrict__ lamda)
{
    __shared__ short bB[16384];                  // 32768 B multi-purpose
    __shared__ unsigned int colh[CHUNK * 4];     // 8192 B: [col][hi]

    const int tid  = threadIdx.x;
    const int lane = tid & 63;
    const int w    = tid >> 6;                   // 0..7
    const int bid  = blockIdx.x;
    const int ck   = bid & (CHUNKS - 1);
    const int rb   = (bid >> 4) & (ROWBLKS - 1);
    const int b    = bid >> 8;

    const int col0 = ck * CHUNK;
    const float* asrc = pred   + (size_t)b * NPTS * 3;
    const float* bsrc = target + (size_t)b * NPTS * 3;

    // ---- hoisted global loads: 1 A-row + 1 B-col per thread
    const int ag = rb * ROWS_PER_BLOCK + tid;
    float ax = asrc[3 * ag + 0], ay = asrc[3 * ag + 1], az = asrc[3 * ag + 2];
    const int bg = col0 + tid;
    float bx = bsrc[3 * bg + 0], by = bsrc[3 * bg + 1], bz = bsrc[3 * bg + 2];

    if (bid == 0 && tid == 0) out[0] = lamda[0] * bpp[0];  // init for atomicAdd

    for (int i = tid; i < CHUNK * 4; i += 512) colh[i] = 0x7F7F7F7Fu;

    // ---- Phase 1: A-encode, wave-local 2 KB region: record for row
    //      (w*64 + lane) at w*2048 + (lane>>4)*512 + (lane&15)*32.
    encA16(ax, ay, az,
           (char*)bB + w * 2048 + (lane >> 4) * 512 + (lane & 15) * 32);

    // ---- Phase 2: wave-local A readback (same wave wrote it; lgkmcnt only)
    afrag af[ITILES];
    {
        const char* ab = (const char*)bB + w * 2048 + (lane & 15) * 32;
        const int hi = lane >> 4;
#pragma unroll
        for (int it = 0; it < ITILES; ++it)
            af[it] = ld_frag(ab + it * 512, hi);
    }
    __syncthreads();   // all waves done reading A before B overwrites bB

    // ---- Phase 3: B-encode from hoisted registers (1 col per thread):
    //      tile tid>>4, col-in-tile tid&15 -> 32 tiles x 512 B = 16 KB.
    encB16(bx, by, bz, (char*)bB + (tid >> 4) * 512 + (tid & 15) * 32);

    f32x4 rmin[ITILES];
#pragma unroll
    for (int it = 0; it < ITILES; ++it) {
        rmin[it][0] = 3e38f; rmin[it][1] = 3e38f;
        rmin[it][2] = 3e38f; rmin[it][3] = 3e38f;
    }
    const f32x4 zf = {0.f, 0.f, 0.f, 0.f};

    __syncthreads();  // B encode + colh init visible

    // ---- Phase 4: main loop, 1-pair-deep prefetch, wrap-clamped
    const char* bb = (const char*)bB + (lane & 15) * 32;
    const int hi = lane >> 4;
    afrag B0 = ld_frag(bb, hi);
    afrag B1 = ld_frag(bb + 512, hi);
    int cbase = (lane & 15) * 4 + hi;               // colh idx = col*4 + hi
    for (int jt = 0; jt < JT; jt += 2) {
        int nj = (jt + 2) & (JT - 1);               // last iter wraps: valid
        afrag Bn0 = ld_frag(bb + nj * 512, hi);     // addr, value unused
        afrag Bn1 = ld_frag(bb + (nj + 1) * 512, hi);
        tile_pair(af, B0, B1, rmin, colh, cbase, zf);
        cbase += 128;                               // 32 cols * 4
        B0 = Bn0; B1 = Bn1;
    }

    __syncthreads();   // main loop done: bB (B-tiles) dead, colh complete

    // ---- row-min epilogue (round-9 verified): stage rmin through bB,
    //      wave-local, 2 passes, stride-80 rows, b128 readback, 1 shfl.
    {
        char* sb = (char*)bB + w * 2560;          // 8 waves x 2560 = 20 KB
        const int hig = lane >> 4, col = lane & 15;
#pragma unroll
        for (int p = 0; p < 2; ++p) {
#pragma unroll
            for (int halfit = 0; halfit < 2; ++halfit) {
#pragma unroll
                for (int r = 0; r < 4; ++r) {
                    int row32 = halfit * 16 + hig * 4 + r;
                    *(float*)(sb + row32 * 80 + col * 4) = rmin[p * 2 + halfit][r];
                }
            }
            const int a = lane >> 1, bsel = lane & 1;
            const char* rp = sb + a * 80 + bsel * 32;
            f32x4 v0 = *(const f32x4*)(rp);
            f32x4 v1 = *(const f32x4*)(rp + 16);
            float v = fminf(fminf(fminf(v0[0], v0[1]), fminf(v0[2], v0[3])),
                            fminf(fminf(v1[0], v1[1]), fminf(v1[2], v1[3])));
            v = fminf(v, __shfl_xor(v, 1, 64));
            if (bsel == 0) {
                int row = rb * ROWS_PER_BLOCK + w * ROWS_PER_WAVE + p * 32 + a;
                rowpart[((size_t)(b * CHUNKS) + ck) * NPTS + row] = fmaxf(v, 0.f);
            }
            __builtin_amdgcn_sched_barrier(0);   // pin pass-1 writes after pass-0 reads
        }
    }

    // ---- col epilogue: merge 4 hi-groups (one uint4 read), coalesced store
    for (int i = tid; i < CHUNK; i += 512) {
        uint4 v = *(const uint4*)&colh[i * 4];
        unsigned int m = umn(umn(v.x, v.y), umn(v.z, v.w));
        colpart[((size_t)(b * ROWBLKS) + rb) * NPTS + col0 + i] = __uint_as_float(m);
    }
}

// min over 16 slices per row/col cell, block-sum, one atomicAdd per block.
// out was initialized to lamda*bpp by chamfer_fused (stream-ordered).
__global__ __launch_bounds__(256) void reduce_partials(
    const float* __restrict__ rowpart, const float* __restrict__ colpart,
    float* __restrict__ out)
{
    const int tid = threadIdx.x;
    const int gt  = blockIdx.x * 256 + tid;    // 0..16383
    float s = 0.f;
#pragma unroll
    for (int a = 0; a < 2; a++) {
        const float* P = a ? colpart : rowpart;
#pragma unroll
        for (int cc = 0; cc < 2; cc++) {
            int c = gt + cc * 16384;           // 0..32767
            int b = c >> 13, r = c & 8191;
            const float* p = P + (size_t)b * 16 * NPTS + r;
            float m = p[0];
#pragma unroll
            for (int k = 1; k < 16; k++)
                m = fminf(m, p[(size_t)k * NPTS]);
            s += m;
        }
    }
#pragma unroll
    for (int off = 32; off > 0; off >>= 1) s += __shfl_down(s, off, 64);
    __shared__ float red[4];
    int lane = tid & 63, wid = tid >> 6;
    if (lane == 0) red[wid] = s;
    __syncthreads();
    if (tid == 0)
        atomicAdd(out, (red[0] + red[1] + red[2] + red[3]) * (1.0f / 32768.0f));
}

// ---------------------------------------------------------------------------
// Fallback: VALU kernel + atomic partmin (tiny workspace only)
// ---------------------------------------------------------------------------
#define T 256
#define Q 8
#define S 16
#define CH 512
#define NCOMBO 8

__global__ __launch_bounds__(T) void chamfer_partial(
    const float* __restrict__ pred, const float* __restrict__ target,
    unsigned int* __restrict__ partmin)
{
    __shared__ float4 db[CH + 2];

    const int bid   = blockIdx.x;
    const int dbc   = bid & (S - 1);
    const int qc    = (bid >> 4) & 3;
    const int combo = bid >> 6;
    const int dir   = combo & 1;
    const int b     = combo >> 1;

    const float* qptr = (dir == 0 ? pred : target) + (size_t)b * NPTS * 3;
    const float* dptr = (dir == 0 ? target : pred) + (size_t)b * NPTS * 3;

    const int tid = threadIdx.x;

    for (int p = tid; p < CH; p += T) {
        int gj = dbc * CH + p;
        float x = dptr[gj * 3 + 0];
        float y = dptr[gj * 3 + 1];
        float z = dptr[gj * 3 + 2];
        db[p] = make_float4(-2.f * x, -2.f * y, -2.f * z,
                            x * x + y * y + z * z);
    }

    float qx[Q], qy[Q], qz[Q], m[Q];
    int qi0 = qc * (T * Q) + tid;
#pragma unroll
    for (int k = 0; k < Q; k++) {
        int qi = qi0 + k * T;
        qx[k] = qptr[qi * 3 + 0];
        qy[k] = qptr[qi * 3 + 1];
        qz[k] = qptr[qi * 3 + 2];
        m[k]  = 3.4e38f;
    }
    __syncthreads();

    float4 c0 = db[0], c1 = db[1];
    for (int j = 0; j < CH; j += 2) {
        float4 n0 = db[j + 2];
        float4 n1 = db[j + 3];
#pragma unroll
        for (int k = 0; k < Q; k++) {
            float s0 = fmaf(c0.x, qx[k], fmaf(c0.y, qy[k], fmaf(c0.z, qz[k], c0.w)));
            float s1 = fmaf(c1.x, qx[k], fmaf(c1.y, qy[k], fmaf(c1.z, qz[k], c1.w)));
            m[k] = fminf(m[k], fminf(s0, s1));
        }
        c0 = n0; c1 = n1;
    }

#pragma unroll
    for (int k = 0; k < Q; k++) {
        int qi = qi0 + k * T;
        float qq = fmaf(qx[k], qx[k], fmaf(qy[k], qy[k], qz[k] * qz[k]));
        float d2 = fmaxf(m[k] + qq, 0.0f);
        atomicMin(&partmin[combo * NPTS + qi], __float_as_uint(d2));
    }
}

__global__ __launch_bounds__(1024) void reduce_final(
    const unsigned int* __restrict__ partmin,
    const float* __restrict__ bpp, const float* __restrict__ lamda,
    float* __restrict__ out)
{
    const int tid = threadIdx.x;
    float s = 0.f;
#pragma unroll
    for (int k = 0; k < (NCOMBO * NPTS) / 1024; k++)
        s += __uint_as_float(partmin[tid + k * 1024]);

#pragma unroll
    for (int off = 32; off > 0; off >>= 1)
        s += __shfl_down(s, off, 64);

    __shared__ float red[16];
    int lane = tid & 63, wid = tid >> 6;
    if (lane == 0) red[wid] = s;
    __syncthreads();
    if (wid == 0) {
        s = (lane < 16) ? red[lane] : 0.f;
#pragma unroll
        for (int off = 8; off > 0; off >>= 1)
            s += __shfl_down(s, off, 64);
        if (lane == 0)
            out[0] = s * (1.0f / 32768.0f) + lamda[0] * bpp[0];
    }
}

extern "C" void kernel_launch(void* const* d_in, const int* in_sizes, int n_in,
                              void* d_out, int out_size, void* d_ws, size_t ws_size,
                              hipStream_t stream) {
    const float* pred   = (const float*)d_in[0];
    const float* target = (const float*)d_in[1];
    const float* bpp    = (const float*)d_in[2];
    const float* lamda  = (const float*)d_in[3];

    const size_t part_bytes = (size_t)NB * 16 * NPTS * sizeof(float);  // 2 MB

    if (ws_size >= 2 * part_bytes) {
        float* rowpart = (float*)d_ws;
        float* colpart = rowpart + (size_t)NB * 16 * NPTS;
        chamfer_fused<<<NB * ROWBLKS * CHUNKS, 512, 0, stream>>>(
            pred, target, rowpart, colpart, (float*)d_out, bpp, lamda);
        reduce_partials<<<64, 256, 0, stream>>>(rowpart, colpart, (float*)d_out);
    } else {
        unsigned int* partmin = (unsigned int*)d_ws;
        hipMemsetAsync(partmin, 0x7F, (size_t)NCOMBO * NPTS * sizeof(unsigned int),
                       stream);
        chamfer_partial<<<NCOMBO * 4 * S, T, 0, stream>>>(pred, target, partmin);
        reduce_final<<<1, 1024, 0, stream>>>(partmin, bpp, lamda, (float*)d_out);
    }
}